// Round 9
// baseline (656.625 us; speedup 1.0000x reference)
//
#include <hip/hip_runtime.h>
#include <math.h>

// EGAT GNN forward — round 9: GEMM restructured for latency. Full-K LDS staging
// (KTILE panels, one barrier for K<=64 kernels), EPI3 epilogue xi/xj gathers
// prefetched at kernel start so they overlap staging+MFMA. Same math as R8.
#define NN 50000      // N_NODES
#define NE 320000     // N_EDGES
#define BATCH 4096

typedef __bf16 bf16x8 __attribute__((ext_vector_type(8)));
typedef float floatx4 __attribute__((ext_vector_type(4)));
typedef unsigned short ushort;
typedef unsigned int uint;

__device__ __forceinline__ float lrelu02(float x) { return x > 0.f ? x : 0.2f * x; }
__device__ __forceinline__ float b2f(ushort h) { return __uint_as_float(((uint)h) << 16); }
__device__ __forceinline__ float b2f_lo(uint u) { return __uint_as_float(u << 16); }
__device__ __forceinline__ float b2f_hi(uint u) { return __uint_as_float(u & 0xffff0000u); }
__device__ __forceinline__ ushort f2b(float x) {
    uint u = __float_as_uint(x);
    return (ushort)((u + 0x7fffu + ((u >> 16) & 1u)) >> 16);  // RNE
}
__device__ __forceinline__ void unpack8(uint4 v, float* f) {
    f[0] = b2f_lo(v.x); f[1] = b2f_hi(v.x); f[2] = b2f_lo(v.y); f[3] = b2f_hi(v.y);
    f[4] = b2f_lo(v.z); f[5] = b2f_hi(v.z); f[6] = b2f_lo(v.w); f[7] = b2f_hi(v.w);
}

// ---------------------------------------------------------------------------
// bf16 MFMA GEMM, C tile 64 x 16*NT per block (4 waves). A (M x K, lda) bf16
// or fp32 (AF32: convert during staging; cols >= Kreal read 0). If ridx !=
// nullptr, A row gr is gathered from ridx[gr]. Bt = B^T ((16*NT) x K bf16).
// KTILE (32 or 64) cols staged per barrier round; LDS panelized in 32-col
// panels (per-panel layout identical to the measured-good R8 layout).
// Epilogues:
//  EPI 1 (NT=4): +bias, act (0=ELU, 1=lrelu0.01), bf16 write row-major ld 64.
//  EPI 2 (NT=16): lane-permuted xfull write.
//  EPI 3 (NT=8): score epilogue, rows = CSR positions; xi/xj gathers are
//                PREFETCHED at kernel start (overlap staging+MFMA).
// ---------------------------------------------------------------------------
template <int NT, int EPI, int AF32, int KTILE>
__global__ __launch_bounds__(256) void gemm_bf16(
    const void* __restrict__ Av, int lda, int M, int K, int Kreal,
    const ushort* __restrict__ Bt,
    ushort* __restrict__ outb,
    const float* __restrict__ bias, int act,
    const int* __restrict__ ridx,
    const int* __restrict__ srcv, const int* __restrict__ dstv,
    const ushort* __restrict__ xfull, const float* __restrict__ attn,
    float* __restrict__ scv)
{
    constexpr int NC = 16 * NT;
    constexpr int PAN = KTILE / 32;
    __shared__ __align__(16) ushort As[PAN * 64 * 32];
    __shared__ __align__(16) ushort Bs[PAN * NC * 32];
    const int tid = threadIdx.x;
    const int row0 = blockIdx.x << 6;
    const int w = tid >> 6, lane = tid & 63;
    const int quad = lane >> 4, l16 = lane & 15;
    const int arow = tid >> 2, asub = tid & 3;
    // hoisted A-row indirection
    int agrow = -1;
    if (row0 + arow < M) agrow = ridx ? ridx[row0 + arow] : (row0 + arow);

    // EPI3: prefetch epilogue gathers NOW — latency hides under staging+MFMA
    uint4 pxi[4], pxj[4];
    if (EPI == 3) {
#pragma unroll
        for (int r = 0; r < 4; r++) {
            int gr = row0 + 16 * w + quad * 4 + r;
            if (gr < M) {
                int s = srcv[gr], d = dstv[gr];
                pxi[r] = *(const uint4*)(xfull + (size_t)s * 256 + l16 * 8);
                pxj[r] = *(const uint4*)(xfull + (size_t)d * 256 + 128 + l16 * 8);
            }
        }
    }

    floatx4 acc[NT];
#pragma unroll
    for (int c = 0; c < NT; c++)
#pragma unroll
        for (int r = 0; r < 4; r++) acc[c][r] = 0.f;

    for (int kt = 0; kt < K; kt += KTILE) {
        // A staging: 4 threads/row, each stages KTILE/4 cols in 8-col units
#pragma unroll
        for (int u = 0; u < PAN; u++) {
            int colb = asub * (KTILE / 4) + u * 8;
            uint4 av = make_uint4(0u, 0u, 0u, 0u);
            if (AF32) {
                if (agrow >= 0 && kt + colb < Kreal) {
                    const float* ap = (const float*)Av + (size_t)agrow * lda + kt + colb;
                    float4 f0 = *(const float4*)ap;
                    float4 f1 = *(const float4*)(ap + 4);
                    av.x = (uint)f2b(f0.x) | ((uint)f2b(f0.y) << 16);
                    av.y = (uint)f2b(f0.z) | ((uint)f2b(f0.w) << 16);
                    av.z = (uint)f2b(f1.x) | ((uint)f2b(f1.y) << 16);
                    av.w = (uint)f2b(f1.z) | ((uint)f2b(f1.w) << 16);
                }
            } else {
                if (agrow >= 0)
                    av = *(const uint4*)((const ushort*)Av + (size_t)agrow * lda + kt + colb);
            }
            int p = colb >> 5;
            *(uint4*)(As + p * 2048 + arow * 32 + (colb & 31)) = av;
        }
        // B staging
#pragma unroll
        for (int it = 0; it < (NC * KTILE) / 2048; it++) {
            int idx = it * 256 + tid;                 // uint4 index
            int bn = idx / (KTILE / 8);
            int bk = (idx % (KTILE / 8)) * 8;
            int p = bk >> 5;
            *(uint4*)(Bs + p * NC * 32 + bn * 32 + (bk & 31)) =
                *(const uint4*)(Bt + (size_t)bn * K + kt + bk);
        }
        __syncthreads();
#pragma unroll
        for (int ks = 0; ks < PAN; ks++) {
            bf16x8 af = *(const bf16x8*)(As + ks * 2048 + (16 * w + l16) * 32 + quad * 8);
#pragma unroll
            for (int c = 0; c < NT; c++) {
                bf16x8 bfv = *(const bf16x8*)(Bs + ks * NC * 32 + (16 * c + l16) * 32 + quad * 8);
                acc[c] = __builtin_amdgcn_mfma_f32_16x16x32_bf16(af, bfv, acc[c], 0, 0, 0);
            }
        }
        if (kt + KTILE < K) __syncthreads();
    }

    if (EPI == 1) {
#pragma unroll
        for (int r = 0; r < 4; r++) {
            int gr = row0 + 16 * w + quad * 4 + r;
            if (gr < M) {
#pragma unroll
                for (int c = 0; c < NT; c++) {
                    int col = 16 * c + l16;
                    float v = acc[c][r] + bias[col];
                    if (act == 0) v = v > 0.f ? v : (__expf(v) - 1.f);
                    else          v = v > 0.f ? v : 0.01f * v;
                    outb[(size_t)gr * 64 + col] = f2b(v);
                }
            }
        }
    } else if (EPI == 2) {
#pragma unroll
        for (int r = 0; r < 4; r++) {
            int gr = row0 + 16 * w + quad * 4 + r;
            if (gr < M) {
                uint4 o0, o1;
                o0.x = (uint)f2b(acc[0][r])  | ((uint)f2b(acc[1][r])  << 16);
                o0.y = (uint)f2b(acc[2][r])  | ((uint)f2b(acc[3][r])  << 16);
                o0.z = (uint)f2b(acc[4][r])  | ((uint)f2b(acc[5][r])  << 16);
                o0.w = (uint)f2b(acc[6][r])  | ((uint)f2b(acc[7][r])  << 16);
                o1.x = (uint)f2b(acc[8][r])  | ((uint)f2b(acc[9][r])  << 16);
                o1.y = (uint)f2b(acc[10][r]) | ((uint)f2b(acc[11][r]) << 16);
                o1.z = (uint)f2b(acc[12][r]) | ((uint)f2b(acc[13][r]) << 16);
                o1.w = (uint)f2b(acc[14][r]) | ((uint)f2b(acc[15][r]) << 16);
                *(uint4*)(outb + (size_t)gr * 256 + l16 * 8) = o0;
                *(uint4*)(outb + (size_t)gr * 256 + 128 + l16 * 8) = o1;
            }
        }
    } else if (EPI == 3) {
        float av8[8];
#pragma unroll
        for (int c = 0; c < 8; c++)
            av8[c] = attn[(c >> 1) * 32 + (c & 1) * 16 + l16];
#pragma unroll
        for (int r = 0; r < 4; r++) {
            int gr = row0 + 16 * w + quad * 4 + r;
            if (gr < M) {
                float xi8[8], xj8[8];
                unpack8(pxi[r], xi8);
                unpack8(pxj[r], xj8);
                float ph[4] = {0.f, 0.f, 0.f, 0.f};
#pragma unroll
                for (int c = 0; c < 8; c++) {
                    float f = lrelu02(acc[c][r] + xi8[c] + xj8[c]);
                    ph[c >> 1] = fmaf(f, av8[c], ph[c >> 1]);
                }
#pragma unroll
                for (int m = 1; m < 16; m <<= 1) {
#pragma unroll
                    for (int h = 0; h < 4; h++) ph[h] += __shfl_xor(ph[h], m);
                }
                if (l16 == 0)
                    *(float4*)(scv + (size_t)gr * 4) =
                        make_float4(ph[0], ph[1], ph[2], ph[3]);
            }
        }
    }
}

// ---------------------------------------------------------------------------
// CSR build: deg histogram -> hierarchical exclusive scan -> fused scatter
// ---------------------------------------------------------------------------
__global__ void k_count(const int* __restrict__ dst, int* __restrict__ deg, int E)
{
    for (int i = blockIdx.x * blockDim.x + threadIdx.x; i < E; i += gridDim.x * blockDim.x)
        atomicAdd(&deg[dst[i]], 1);
}

__global__ __launch_bounds__(256) void scan_local(
    const int* __restrict__ deg, int* __restrict__ rowptr, int* __restrict__ partials, int N)
{
    __shared__ int sd[256];
    int tid = threadIdx.x;
    int i = blockIdx.x * 256 + tid;
    int v = (i < N) ? deg[i] : 0;
    sd[tid] = v; __syncthreads();
#pragma unroll
    for (int off = 1; off < 256; off <<= 1) {
        int t = (tid >= off) ? sd[tid - off] : 0;
        __syncthreads();
        sd[tid] += t;
        __syncthreads();
    }
    if (i < N) rowptr[i] = sd[tid] - v;
    if (tid == 255) partials[blockIdx.x] = sd[255];
}

__global__ __launch_bounds__(256) void scan_partials(int* __restrict__ partials, int nb)
{
    __shared__ int sd[256];
    int tid = threadIdx.x;
    int v = (tid < nb) ? partials[tid] : 0;
    sd[tid] = v; __syncthreads();
#pragma unroll
    for (int off = 1; off < 256; off <<= 1) {
        int t = (tid >= off) ? sd[tid - off] : 0;
        __syncthreads();
        sd[tid] += t;
        __syncthreads();
    }
    if (tid < nb) partials[tid] = sd[tid] - v;
}

__global__ void scan_add(int* __restrict__ rowptr, const int* __restrict__ partials, int N, int E)
{
    int i = blockIdx.x * 256 + threadIdx.x;
    if (i < N) rowptr[i] += partials[i >> 8];
    if (i == 0) rowptr[N] = E;
}

// scatter + permute fused: p = CSR position of edge i; emit srcp/dstp/eidx/m1p/m2p.
__global__ void k_scatter_perm(const int* __restrict__ dst, const int* __restrict__ rowptr,
                               int* __restrict__ cnt, const int* __restrict__ src,
                               const float* __restrict__ m1, const float* __restrict__ m2,
                               int* __restrict__ srcp, int* __restrict__ dstp,
                               int* __restrict__ eidx,
                               float* __restrict__ m1p, float* __restrict__ m2p, int E)
{
    for (int i = blockIdx.x * blockDim.x + threadIdx.x; i < E; i += gridDim.x * blockDim.x) {
        int d = dst[i];
        int p = rowptr[d] + atomicAdd(&cnt[d], 1);
        srcp[p] = src[i];
        dstp[p] = d;
        eidx[p] = i;
        m1p[p] = m1[i];
        m2p[p] = m2[i];
    }
}

__global__ void k_cvt(const float* __restrict__ in, ushort* __restrict__ out, int n)
{
    for (int i = blockIdx.x * blockDim.x + threadIdx.x; i < n; i += gridDim.x * blockDim.x)
        out[i] = f2b(in[i]);
}

// ---------------------------------------------------------------------------
// Weight prep, all 4 EGATs at once. egat e: 0=loc l0, 1=glob l0, 2=loc l1, 3=glob l1.
// ---------------------------------------------------------------------------
__global__ void k_prep_ninj_all(const float* __restrict__ loc_wni, const float* __restrict__ loc_wnj,
                                const float* __restrict__ glob_wni, const float* __restrict__ glob_wnj,
                                ushort* __restrict__ B)  // 4 x (256 x 64)
{
    int e = blockIdx.x >> 6;
    int idx = (blockIdx.x & 63) * 256 + threadIdx.x;  // 16384
    int layer = e >> 1, gl = e & 1;
    const float* wni = (gl ? glob_wni : loc_wni) + layer * 64 * 128;
    const float* wnj = (gl ? glob_wnj : loc_wnj) + layer * 64 * 128;
    int n = idx >> 6, k = idx & 63;
    float v = (n < 128) ? wni[k * 128 + n] : wnj[k * 128 + (n - 128)];
    B[e * 16384 + idx] = f2b(v);
}

__global__ void k_prep_we_all(const float* __restrict__ loc_we, const float* __restrict__ glob_we,
                              ushort* __restrict__ B)  // 4 slots; loc 128x32 (K pad), glob 128x64
{
    int b = blockIdx.x;
    int e, K, Kreal, idx;
    const float* we;
    if (b < 32) { int layer = b >> 4; e = layer * 2; K = 32; Kreal = 16;
                  we = loc_we + layer * 16 * 128; idx = (b & 15) * 256 + threadIdx.x; }
    else        { int layer = (b - 32) >> 5; e = layer * 2 + 1; K = 64; Kreal = 64;
                  we = glob_we + layer * 64 * 128; idx = ((b - 32) & 31) * 256 + threadIdx.x; }
    int n = idx / K, k = idx % K;
    B[e * 8192 + idx] = (k < Kreal) ? f2b(we[k * 128 + n]) : (ushort)0;
}

// W'[h*64+i, j] = sum_k wnode[i, h*64+k] * aggw[h*64+k, j]; stored transposed (64 x 256)
__global__ void k_fold_all(const float* __restrict__ loc_wnode, const float* __restrict__ agg1_w,
                           const float* __restrict__ glob_wnode, const float* __restrict__ agg2_w,
                           ushort* __restrict__ B)  // 4 x (64 x 256)
{
    int e = blockIdx.x >> 6;
    int idx = (blockIdx.x & 63) * 256 + threadIdx.x;  // 16384
    int layer = e >> 1, gl = e & 1;
    const float* wnode = (gl ? glob_wnode : loc_wnode) + layer * 64 * 256;
    const float* aggw  = (gl ? agg2_w : agg1_w) + layer * 256 * 64;
    int j = idx >> 8, col = idx & 255;
    int h = col >> 6, ii = col & 63;
    float s = 0.f;
#pragma unroll 8
    for (int k = 0; k < 64; k++)
        s = fmaf(wnode[ii * 256 + h * 64 + k], aggw[(h * 64 + k) * 64 + j], s);
    B[e * 16384 + j * 256 + col] = f2b(s);
}

// ---------------------------------------------------------------------------
// Node kernel, zero cross-lane ops: one 16-lane group per node (all 4 heads),
// 16 groups per block, grid NN/16.
// ---------------------------------------------------------------------------
__global__ __launch_bounds__(256) void node_fused(
    const float* __restrict__ scv,      // E x 4 fp32 (CSR order)
    const int* __restrict__ rowptr, const int* __restrict__ srcp,
    const float* __restrict__ maskp,
    const ushort* __restrict__ hsrc,    // N x 64 bf16 (layer input)
    ushort* __restrict__ zb)            // N x 256 bf16
{
    int tid = threadIdx.x;
    int n = (blockIdx.x << 4) | (tid >> 4);   // 16 groups/block, one node each
    int sl = tid & 15;
    int beg = rowptr[n], end = rowptr[n + 1];
    float l0 = 0.f, l1 = 0.f, l2 = 0.f, l3 = 0.f;
    float acc[4][4] = {};
#pragma unroll 2
    for (int i = beg; i < end; i++) {
        float4 s4 = *(const float4*)(scv + (size_t)i * 4);   // broadcast in group
        float mk = maskp[i];
        int s = srcp[i];
        uint2 hvv = *(const uint2*)(hsrc + (size_t)s * 64 + sl * 4);  // 128B/group
        float t0 = __expf(s4.x), t1 = __expf(s4.y), t2 = __expf(s4.z), t3 = __expf(s4.w);
        l0 += t0; l1 += t1; l2 += t2; l3 += t3;
        float a0 = t0 * mk, a1 = t1 * mk, a2 = t2 * mk, a3 = t3 * mk;
        float hv[4] = { b2f_lo(hvv.x), b2f_hi(hvv.x), b2f_lo(hvv.y), b2f_hi(hvv.y) };
#pragma unroll
        for (int c = 0; c < 4; c++) {
            acc[0][c] = fmaf(a0, hv[c], acc[0][c]);
            acc[1][c] = fmaf(a1, hv[c], acc[1][c]);
            acc[2][c] = fmaf(a2, hv[c], acc[2][c]);
            acc[3][c] = fmaf(a3, hv[c], acc[3][c]);
        }
    }
    float inv[4] = { 1.f / (l0 + 1e-9f), 1.f / (l1 + 1e-9f),
                     1.f / (l2 + 1e-9f), 1.f / (l3 + 1e-9f) };
#pragma unroll
    for (int h = 0; h < 4; h++) {
        uint2 o;
        o.x = (uint)f2b(acc[h][0] * inv[h]) | ((uint)f2b(acc[h][1] * inv[h]) << 16);
        o.y = (uint)f2b(acc[h][2] * inv[h]) | ((uint)f2b(acc[h][3] * inv[h]) << 16);
        *(uint2*)(zb + (size_t)n * 256 + h * 64 + sl * 4) = o;
    }
}

// ---------------------------------------------------------------------------
// Final MLP heads. One wave per batch row.
// ---------------------------------------------------------------------------
__global__ __launch_bounds__(256) void final_ui(
    const ushort* __restrict__ s0, const ushort* __restrict__ s1,
    const int* __restrict__ uidx, const int* __restrict__ iidx,
    const float* __restrict__ w1, const float* __restrict__ b1,
    const float* __restrict__ w2, const float* __restrict__ b2, float* __restrict__ out)
{
    __shared__ float xs[4][256];
    int tid = threadIdx.x, wid = tid >> 6, lane = tid & 63;
    int r = (blockIdx.x << 2) + wid;
    int u = uidx[r], it = iidx[r];
    xs[wid][lane]       = b2f(s0[(size_t)u * 64 + lane]);
    xs[wid][64 + lane]  = b2f(s1[(size_t)u * 64 + lane]);
    xs[wid][128 + lane] = b2f(s0[(size_t)it * 64 + lane]);
    xs[wid][192 + lane] = b2f(s1[(size_t)it * 64 + lane]);
    __syncthreads();
    int c = lane << 1;
    float a0 = b1[c], a1 = b1[c + 1];
    for (int k = 0; k < 256; k++) {
        float xv = xs[wid][k];
        float2 wv = *(const float2*)(w1 + (size_t)k * 128 + c);
        a0 = fmaf(xv, wv.x, a0);
        a1 = fmaf(xv, wv.y, a1);
    }
    a0 = fmaxf(a0, 0.f);
    a1 = fmaxf(a1, 0.f);
    float2 w2v = *(const float2*)(w2 + c);
    float p = a0 * w2v.x + a1 * w2v.y;
#pragma unroll
    for (int mm = 1; mm < 64; mm <<= 1) p += __shfl_xor(p, mm);
    if (lane == 0) out[r] = 1.f / (1.f + __expf(-(p + b2[0])));
}

__global__ __launch_bounds__(256) void final_sg(
    const ushort* __restrict__ s0, const ushort* __restrict__ s1,
    const int* __restrict__ gidx,
    const float* __restrict__ w1, const float* __restrict__ b1,
    const float* __restrict__ w2, const float* __restrict__ b2, float* __restrict__ out)
{
    __shared__ float xs[4][128];
    int tid = threadIdx.x, wid = tid >> 6, lane = tid & 63;
    int r = (blockIdx.x << 2) + wid;
    int n = gidx[r];
    xs[wid][lane]      = b2f(s0[(size_t)n * 64 + lane]);
    xs[wid][64 + lane] = b2f(s1[(size_t)n * 64 + lane]);
    __syncthreads();
    int c = lane << 1;
    float a0 = b1[c], a1 = b1[c + 1];
    for (int k = 0; k < 128; k++) {
        float xv = xs[wid][k];
        float2 wv = *(const float2*)(w1 + (size_t)k * 128 + c);
        a0 = fmaf(xv, wv.x, a0);
        a1 = fmaf(xv, wv.y, a1);
    }
    a0 = fmaxf(a0, 0.f);
    a1 = fmaxf(a1, 0.f);
    float2 w2v = *(const float2*)(w2 + c);
    float p = a0 * w2v.x + a1 * w2v.y;
#pragma unroll
    for (int mm = 1; mm < 64; mm <<= 1) p += __shfl_xor(p, mm);
    if (lane == 0) out[r] = 1.f / (1.f + __expf(-(p + b2[0])));
}

// ---------------------------------------------------------------------------
extern "C" void kernel_launch(void* const* d_in, const int* in_sizes, int n_in,
                              void* d_out, int out_size, void* d_ws, size_t ws_size,
                              hipStream_t stream)
{
    const float* x       = (const float*)d_in[0];
    const float* efeat   = (const float*)d_in[1];
    const float* efeat2  = (const float*)d_in[2];
    const float* mask1   = (const float*)d_in[3];
    const float* mask2   = (const float*)d_in[4];
    const int*   src     = (const int*)d_in[5];
    const int*   dst     = (const int*)d_in[6];
    const int*   uidx    = (const int*)d_in[7];
    const int*   iidx    = (const int*)d_in[8];
    const int*   gidx    = (const int*)d_in[9];
    const float* loc_wni = (const float*)d_in[10];
    const float* loc_wnj = (const float*)d_in[11];
    const float* loc_we  = (const float*)d_in[12];
    const float* loc_attn= (const float*)d_in[13];
    const float* loc_wnode=(const float*)d_in[14];
    const float* agg1_w  = (const float*)d_in[15];
    const float* agg1_b  = (const float*)d_in[16];
    const float* glob_wni= (const float*)d_in[17];
    const float* glob_wnj= (const float*)d_in[18];
    const float* glob_we = (const float*)d_in[19];
    const float* glob_attn=(const float*)d_in[20];
    const float* glob_wnode=(const float*)d_in[21];
    const float* agg2_w  = (const float*)d_in[22];
    const float* agg2_b  = (const float*)d_in[23];
    const float* w1_ui   = (const float*)d_in[24];
    const float* b1_ui   = (const float*)d_in[25];
    const float* w1_sg   = (const float*)d_in[26];
    const float* b1_sg   = (const float*)d_in[27];
    const float* w2_ui   = (const float*)d_in[28];
    const float* b2_ui   = (const float*)d_in[29];
    const float* w2_sg   = (const float*)d_in[30];
    const float* b2_sg   = (const float*)d_in[31];

    // workspace carve (all offsets 256B-aligned)
    char* wsp = (char*)d_ws;
    auto carve = [&](size_t bytes) { char* p = wsp; wsp += (bytes + 255) & ~(size_t)255; return p; };
    ushort* xfull = (ushort*)carve((size_t)NN * 256 * 2);   // lane-permuted [xi|xj]
    ushort* zb    = (ushort*)carve((size_t)NN * 256 * 2);
    ushort* hb[5];
    for (int i = 0; i < 5; i++) hb[i] = (ushort*)carve((size_t)NN * 64 * 2);
    float*  scv   = (float*)carve((size_t)NE * 16);
    float*  m1p   = (float*)carve((size_t)NE * 4);
    float*  m2p   = (float*)carve((size_t)NE * 4);
    int*    srcp  = (int*)carve((size_t)NE * 4);
    int*    dstp  = (int*)carve((size_t)NE * 4);
    int*    eidx  = (int*)carve((size_t)NE * 4);
    ushort* Bninj = (ushort*)carve(4 * 16384 * 2);
    ushort* Bwe   = (ushort*)carve(4 * 8192 * 2);
    ushort* Bfold = (ushort*)carve(4 * 16384 * 2);
    int* deg      = (int*)carve(NN * 4);
    int* rowptr   = (int*)carve((NN + 4) * 4);
    int* partials = (int*)carve(256 * 4);

    // ---- weight prep (state-independent) + CSR build + fused scatter ----
    k_prep_ninj_all<<<256, 256, 0, stream>>>(loc_wni, loc_wnj, glob_wni, glob_wnj, Bninj);
    k_prep_we_all<<<96, 256, 0, stream>>>(loc_we, glob_we, Bwe);
    k_fold_all<<<256, 256, 0, stream>>>(loc_wnode, agg1_w, glob_wnode, agg2_w, Bfold);
    hipMemsetAsync(deg, 0, NN * sizeof(int), stream);
    k_count<<<1280, 256, 0, stream>>>(dst, deg, NE);
    scan_local<<<196, 256, 0, stream>>>(deg, rowptr, partials, NN);
    scan_partials<<<1, 256, 0, stream>>>(partials, 196);
    scan_add<<<196, 256, 0, stream>>>(rowptr, partials, NN, NE);
    hipMemsetAsync(deg, 0, NN * sizeof(int), stream);
    k_scatter_perm<<<1280, 256, 0, stream>>>(dst, rowptr, deg, src, mask1, mask2,
                                             srcp, dstp, eidx, m1p, m2p, NE);
    k_cvt<<<3200, 256, 0, stream>>>(x, hb[0], NN * 64);

    auto egat = [&](const ushort* hin, int e, const float* maskp, const float* attn,
                    const float* aggb, int act, ushort* hout) {
        int is_glob = e & 1;
        // xfull = [h@wni | h@wnj], lane-permuted layout (EPI 2), single barrier
        gemm_bf16<16, 2, 0, 64><<<782, 256, 0, stream>>>(hin, 64, NN, 64, 64,
                                                         Bninj + e * 16384, xfull,
                                                         nullptr, 0, nullptr, nullptr,
                                                         nullptr, nullptr, nullptr, nullptr);
        // scores fused into e@we GEMM epilogue (EPI 3), rows in CSR order,
        // epilogue gathers prefetched at kernel start
        if (is_glob)
            gemm_bf16<8, 3, 1, 64><<<5000, 256, 0, stream>>>(efeat2, 64, NE, 64, 64,
                                                             Bwe + e * 8192, nullptr,
                                                             nullptr, 0, eidx, srcp, dstp,
                                                             xfull, attn, scv);
        else
            gemm_bf16<8, 3, 1, 32><<<5000, 256, 0, stream>>>(efeat, 16, NE, 32, 16,
                                                             Bwe + e * 8192, nullptr,
                                                             nullptr, 0, eidx, srcp, dstp,
                                                             xfull, attn, scv);
        node_fused<<<NN / 16, 256, 0, stream>>>(scv, rowptr, srcp, maskp, hin, zb);
        gemm_bf16<4, 1, 0, 64><<<782, 256, 0, stream>>>(zb, 256, NN, 256, 256,
                                                        Bfold + e * 16384, hout,
                                                        aggb, act, nullptr, nullptr,
                                                        nullptr, nullptr, nullptr, nullptr);
    };

    egat(hb[0], 0, m1p, loc_attn,        agg1_b,      0, hb[1]);
    egat(hb[1], 1, m2p, glob_attn,       agg2_b,      1, hb[2]);
    egat(hb[2], 2, m1p, loc_attn + 128,  agg1_b + 64, 0, hb[3]);
    egat(hb[3], 3, m2p, glob_attn + 128, agg2_b + 64, 1, hb[4]);

    float* out = (float*)d_out;
    final_sg<<<BATCH / 4, 256, 0, stream>>>(hb[2], hb[4], gidx, w1_sg, b1_sg, w2_sg, b2_sg, out);
    final_ui<<<BATCH / 4, 256, 0, stream>>>(hb[1], hb[3], uidx, iidx, w1_ui, b1_ui, w2_ui, b2_ui, out + BATCH);
}

// Round 10
// 627.900 us; speedup vs baseline: 1.0457x; 1.0457x over previous
//
#include <hip/hip_runtime.h>
#include <math.h>

// EGAT GNN forward — round 10: wni/wnj folded into the score GEMM K-dimension.
// A-row = [ef | h[src] | h[dst]] (K=160 loc / 192 glob), B = [we; wni; wnj].
// Epilogue has ZERO gathers (pure register math). xfull GEMMs deleted.
// R8 2-phase staging skeleton (12KB LDS) restored; R9 prefetch/KTILE reverted.
#define NN 50000      // N_NODES
#define NE 320000     // N_EDGES
#define BATCH 4096

typedef __bf16 bf16x8 __attribute__((ext_vector_type(8)));
typedef float floatx4 __attribute__((ext_vector_type(4)));
typedef unsigned short ushort;
typedef unsigned int uint;

__device__ __forceinline__ float lrelu02(float x) { return x > 0.f ? x : 0.2f * x; }
__device__ __forceinline__ float b2f(ushort h) { return __uint_as_float(((uint)h) << 16); }
__device__ __forceinline__ float b2f_lo(uint u) { return __uint_as_float(u << 16); }
__device__ __forceinline__ float b2f_hi(uint u) { return __uint_as_float(u & 0xffff0000u); }
__device__ __forceinline__ ushort f2b(float x) {
    uint u = __float_as_uint(x);
    return (ushort)((u + 0x7fffu + ((u >> 16) & 1u)) >> 16);  // RNE
}

// ---------------------------------------------------------------------------
// Score GEMM (one per EGAT): C-rows are edges in CSR order. Per 32-col round,
// the A source switches: ef (fp32, orig order via eidx), then h[src], then
// h[dst] (bf16 gathers; dst CSR-sequential -> L1 reuse). B = [we; wni; wnj]^T
// (128 x KTOT bf16). Epilogue: f=lrelu(acc), ph=f·attn per head, 16-lane
// xor-reduce, one coalesced float4 score per edge. No epilogue gathers.
// ---------------------------------------------------------------------------
__global__ __launch_bounds__(256) void score_gemm(
    const float* __restrict__ ef, int lda_ef, int ef_real, int ef_end, int KTOT,
    const ushort* __restrict__ Bt,    // 128 x KTOT (transposed)
    const ushort* __restrict__ hb,    // N x 64 bf16 layer input
    const int* __restrict__ eidx, const int* __restrict__ srcv,
    const int* __restrict__ dstv,
    const float* __restrict__ attn, float* __restrict__ scv)
{
    __shared__ __align__(16) ushort As[64 * 32];
    __shared__ __align__(16) ushort Bs[128 * 32];
    const int tid = threadIdx.x;
    const int row0 = blockIdx.x << 6;
    const int w = tid >> 6, lane = tid & 63;
    const int quad = lane >> 4, l16 = lane & 15;
    const int arow = tid >> 2, c0 = (tid & 3) << 3;
    const int gr = row0 + arow;                    // < NE (grid exact)
    const int e_o = eidx[gr];
    const ushort* hs = hb + (size_t)srcv[gr] * 64;
    const ushort* hd = hb + (size_t)dstv[gr] * 64;

    floatx4 acc[8];
#pragma unroll
    for (int c = 0; c < 8; c++)
#pragma unroll
        for (int r = 0; r < 4; r++) acc[c][r] = 0.f;

    for (int kt = 0; kt < KTOT; kt += 32) {
        uint4 av = make_uint4(0u, 0u, 0u, 0u);
        if (kt < ef_end) {
            int col = kt + c0;
            if (col < ef_real) {
                const float* ap = ef + (size_t)e_o * lda_ef + col;
                float4 f0 = *(const float4*)ap;
                float4 f1 = *(const float4*)(ap + 4);
                av.x = (uint)f2b(f0.x) | ((uint)f2b(f0.y) << 16);
                av.y = (uint)f2b(f0.z) | ((uint)f2b(f0.w) << 16);
                av.z = (uint)f2b(f1.x) | ((uint)f2b(f1.y) << 16);
                av.w = (uint)f2b(f1.z) | ((uint)f2b(f1.w) << 16);
            }
        } else if (kt < ef_end + 64) {
            av = *(const uint4*)(hs + (kt - ef_end) + c0);
        } else {
            av = *(const uint4*)(hd + (kt - ef_end - 64) + c0);
        }
        *(uint4*)(As + arow * 32 + c0) = av;
#pragma unroll
        for (int it = 0; it < 2; it++) {
            int idx = it * 256 + tid;
            int bn = idx >> 2, bk = (idx & 3) << 3;
            *(uint4*)(Bs + bn * 32 + bk) = *(const uint4*)(Bt + (size_t)bn * KTOT + kt + bk);
        }
        __syncthreads();
        bf16x8 af = *(const bf16x8*)(As + (16 * w + l16) * 32 + quad * 8);
#pragma unroll
        for (int c = 0; c < 8; c++) {
            bf16x8 bfv = *(const bf16x8*)(Bs + (16 * c + l16) * 32 + quad * 8);
            acc[c] = __builtin_amdgcn_mfma_f32_16x16x32_bf16(af, bfv, acc[c], 0, 0, 0);
        }
        if (kt + 32 < KTOT) __syncthreads();
    }

    float av8[8];
#pragma unroll
    for (int c = 0; c < 8; c++)
        av8[c] = attn[(c >> 1) * 32 + (c & 1) * 16 + l16];
#pragma unroll
    for (int r = 0; r < 4; r++) {
        int orow = row0 + 16 * w + quad * 4 + r;
        float ph[4] = {0.f, 0.f, 0.f, 0.f};
#pragma unroll
        for (int c = 0; c < 8; c++) {
            float f = lrelu02(acc[c][r]);
            ph[c >> 1] = fmaf(f, av8[c], ph[c >> 1]);
        }
#pragma unroll
        for (int m = 1; m < 16; m <<= 1) {
#pragma unroll
            for (int h = 0; h < 4; h++) ph[h] += __shfl_xor(ph[h], m);
        }
        if (l16 == 0)
            *(float4*)(scv + (size_t)orow * 4) = make_float4(ph[0], ph[1], ph[2], ph[3]);
    }
}

// ---------------------------------------------------------------------------
// Aggregation GEMM (R8 skeleton): z (M x 256 bf16) @ Bfold^T -> act -> M x 64.
// ---------------------------------------------------------------------------
__global__ __launch_bounds__(256) void gemm_agg(
    const ushort* __restrict__ A, int M,
    const ushort* __restrict__ Bt,    // 64 x 256
    const float* __restrict__ bias, int act,
    ushort* __restrict__ outb)
{
    __shared__ __align__(16) ushort As[64 * 32];
    __shared__ __align__(16) ushort Bs[64 * 32];
    const int tid = threadIdx.x;
    const int row0 = blockIdx.x << 6;
    const int w = tid >> 6, lane = tid & 63;
    const int quad = lane >> 4, l16 = lane & 15;
    const int arow = tid >> 2, c0 = (tid & 3) << 3;
    const int agrow = row0 + arow;

    floatx4 acc[4];
#pragma unroll
    for (int c = 0; c < 4; c++)
#pragma unroll
        for (int r = 0; r < 4; r++) acc[c][r] = 0.f;

    for (int kt = 0; kt < 256; kt += 32) {
        uint4 av = make_uint4(0u, 0u, 0u, 0u);
        if (agrow < M)
            av = *(const uint4*)(A + (size_t)agrow * 256 + kt + c0);
        *(uint4*)(As + arow * 32 + c0) = av;
        {
            int bn = tid >> 2, bk = (tid & 3) << 3;
            *(uint4*)(Bs + bn * 32 + bk) = *(const uint4*)(Bt + (size_t)bn * 256 + kt + bk);
        }
        __syncthreads();
        bf16x8 af = *(const bf16x8*)(As + (16 * w + l16) * 32 + quad * 8);
#pragma unroll
        for (int c = 0; c < 4; c++) {
            bf16x8 bfv = *(const bf16x8*)(Bs + (16 * c + l16) * 32 + quad * 8);
            acc[c] = __builtin_amdgcn_mfma_f32_16x16x32_bf16(af, bfv, acc[c], 0, 0, 0);
        }
        if (kt + 32 < 256) __syncthreads();
    }
#pragma unroll
    for (int r = 0; r < 4; r++) {
        int gr = row0 + 16 * w + quad * 4 + r;
        if (gr < M) {
#pragma unroll
            for (int c = 0; c < 4; c++) {
                int col = 16 * c + l16;
                float v = acc[c][r] + bias[col];
                if (act == 0) v = v > 0.f ? v : (__expf(v) - 1.f);
                else          v = v > 0.f ? v : 0.01f * v;
                outb[(size_t)gr * 64 + col] = f2b(v);
            }
        }
    }
}

// ---------------------------------------------------------------------------
// CSR build: deg histogram -> hierarchical exclusive scan -> fused scatter
// ---------------------------------------------------------------------------
__global__ void k_count(const int* __restrict__ dst, int* __restrict__ deg, int E)
{
    for (int i = blockIdx.x * blockDim.x + threadIdx.x; i < E; i += gridDim.x * blockDim.x)
        atomicAdd(&deg[dst[i]], 1);
}

__global__ __launch_bounds__(256) void scan_local(
    const int* __restrict__ deg, int* __restrict__ rowptr, int* __restrict__ partials, int N)
{
    __shared__ int sd[256];
    int tid = threadIdx.x;
    int i = blockIdx.x * 256 + tid;
    int v = (i < N) ? deg[i] : 0;
    sd[tid] = v; __syncthreads();
#pragma unroll
    for (int off = 1; off < 256; off <<= 1) {
        int t = (tid >= off) ? sd[tid - off] : 0;
        __syncthreads();
        sd[tid] += t;
        __syncthreads();
    }
    if (i < N) rowptr[i] = sd[tid] - v;
    if (tid == 255) partials[blockIdx.x] = sd[255];
}

__global__ __launch_bounds__(256) void scan_partials(int* __restrict__ partials, int nb)
{
    __shared__ int sd[256];
    int tid = threadIdx.x;
    int v = (tid < nb) ? partials[tid] : 0;
    sd[tid] = v; __syncthreads();
#pragma unroll
    for (int off = 1; off < 256; off <<= 1) {
        int t = (tid >= off) ? sd[tid - off] : 0;
        __syncthreads();
        sd[tid] += t;
        __syncthreads();
    }
    if (tid < nb) partials[tid] = sd[tid] - v;
}

__global__ void scan_add(int* __restrict__ rowptr, const int* __restrict__ partials, int N, int E)
{
    int i = blockIdx.x * 256 + threadIdx.x;
    if (i < N) rowptr[i] += partials[i >> 8];
    if (i == 0) rowptr[N] = E;
}

// scatter + permute fused: p = CSR position of edge i; emit srcp/dstp/eidx/m1p/m2p.
__global__ void k_scatter_perm(const int* __restrict__ dst, const int* __restrict__ rowptr,
                               int* __restrict__ cnt, const int* __restrict__ src,
                               const float* __restrict__ m1, const float* __restrict__ m2,
                               int* __restrict__ srcp, int* __restrict__ dstp,
                               int* __restrict__ eidx,
                               float* __restrict__ m1p, float* __restrict__ m2p, int E)
{
    for (int i = blockIdx.x * blockDim.x + threadIdx.x; i < E; i += gridDim.x * blockDim.x) {
        int d = dst[i];
        int p = rowptr[d] + atomicAdd(&cnt[d], 1);
        srcp[p] = src[i];
        dstp[p] = d;
        eidx[p] = i;
        m1p[p] = m1[i];
        m2p[p] = m2[i];
    }
}

__global__ void k_cvt(const float* __restrict__ in, ushort* __restrict__ out, int n)
{
    for (int i = blockIdx.x * blockDim.x + threadIdx.x; i < n; i += gridDim.x * blockDim.x)
        out[i] = f2b(in[i]);
}

// ---------------------------------------------------------------------------
// Weight prep. Bsc[e] = [we | wni | wnj]^T, 128 rows x KTOT cols
// (KTOT = 160 loc / 192 glob; slot stride 24576). Bfold as before.
// ---------------------------------------------------------------------------
__global__ void k_prep_score_all(const float* __restrict__ loc_we, const float* __restrict__ glob_we,
                                 const float* __restrict__ loc_wni, const float* __restrict__ glob_wni,
                                 const float* __restrict__ loc_wnj, const float* __restrict__ glob_wnj,
                                 ushort* __restrict__ B)   // 4 x 24576
{
    int idx = blockIdx.x * 256 + threadIdx.x;   // 4*24576 = 98304
    if (idx >= 4 * 24576) return;
    int e = idx / 24576, rem = idx % 24576;
    int layer = e >> 1, gl = e & 1;
    int KTOT = gl ? 192 : 160;
    int ef_end = gl ? 64 : 32;
    int ef_real = gl ? 64 : 16;
    if (rem >= 128 * KTOT) return;
    int n = rem / KTOT, k = rem % KTOT;
    const float* we  = (gl ? glob_we  + layer * 64 * 128 : loc_we  + layer * 16 * 128);
    const float* wni = (gl ? glob_wni : loc_wni) + layer * 64 * 128;
    const float* wnj = (gl ? glob_wnj : loc_wnj) + layer * 64 * 128;
    float v;
    if (k < ef_end)            v = (k < ef_real) ? we[k * 128 + n] : 0.f;
    else if (k < ef_end + 64)  v = wni[(k - ef_end) * 128 + n];
    else                       v = wnj[(k - ef_end - 64) * 128 + n];
    B[e * 24576 + rem] = f2b(v);
}

// W'[h*64+i, j] = sum_k wnode[i, h*64+k] * aggw[h*64+k, j]; stored transposed (64 x 256)
__global__ void k_fold_all(const float* __restrict__ loc_wnode, const float* __restrict__ agg1_w,
                           const float* __restrict__ glob_wnode, const float* __restrict__ agg2_w,
                           ushort* __restrict__ B)  // 4 x (64 x 256)
{
    int e = blockIdx.x >> 6;
    int idx = (blockIdx.x & 63) * 256 + threadIdx.x;  // 16384
    int layer = e >> 1, gl = e & 1;
    const float* wnode = (gl ? glob_wnode : loc_wnode) + layer * 64 * 256;
    const float* aggw  = (gl ? agg2_w : agg1_w) + layer * 256 * 64;
    int j = idx >> 8, col = idx & 255;
    int h = col >> 6, ii = col & 63;
    float s = 0.f;
#pragma unroll 8
    for (int k = 0; k < 64; k++)
        s = fmaf(wnode[ii * 256 + h * 64 + k], aggw[(h * 64 + k) * 64 + j], s);
    B[e * 16384 + j * 256 + col] = f2b(s);
}

// ---------------------------------------------------------------------------
// Node kernel, zero cross-lane ops: one 16-lane group per node (all 4 heads),
// 16 groups per block, grid NN/16.
// ---------------------------------------------------------------------------
__global__ __launch_bounds__(256) void node_fused(
    const float* __restrict__ scv,      // E x 4 fp32 (CSR order)
    const int* __restrict__ rowptr, const int* __restrict__ srcp,
    const float* __restrict__ maskp,
    const ushort* __restrict__ hsrc,    // N x 64 bf16 (layer input)
    ushort* __restrict__ zb)            // N x 256 bf16
{
    int tid = threadIdx.x;
    int n = (blockIdx.x << 4) | (tid >> 4);   // 16 groups/block, one node each
    int sl = tid & 15;
    int beg = rowptr[n], end = rowptr[n + 1];
    float l0 = 0.f, l1 = 0.f, l2 = 0.f, l3 = 0.f;
    float acc[4][4] = {};
#pragma unroll 2
    for (int i = beg; i < end; i++) {
        float4 s4 = *(const float4*)(scv + (size_t)i * 4);   // broadcast in group
        float mk = maskp[i];
        int s = srcp[i];
        uint2 hvv = *(const uint2*)(hsrc + (size_t)s * 64 + sl * 4);  // 128B/group
        float t0 = __expf(s4.x), t1 = __expf(s4.y), t2 = __expf(s4.z), t3 = __expf(s4.w);
        l0 += t0; l1 += t1; l2 += t2; l3 += t3;
        float a0 = t0 * mk, a1 = t1 * mk, a2 = t2 * mk, a3 = t3 * mk;
        float hv[4] = { b2f_lo(hvv.x), b2f_hi(hvv.x), b2f_lo(hvv.y), b2f_hi(hvv.y) };
#pragma unroll
        for (int c = 0; c < 4; c++) {
            acc[0][c] = fmaf(a0, hv[c], acc[0][c]);
            acc[1][c] = fmaf(a1, hv[c], acc[1][c]);
            acc[2][c] = fmaf(a2, hv[c], acc[2][c]);
            acc[3][c] = fmaf(a3, hv[c], acc[3][c]);
        }
    }
    float inv[4] = { 1.f / (l0 + 1e-9f), 1.f / (l1 + 1e-9f),
                     1.f / (l2 + 1e-9f), 1.f / (l3 + 1e-9f) };
#pragma unroll
    for (int h = 0; h < 4; h++) {
        uint2 o;
        o.x = (uint)f2b(acc[h][0] * inv[h]) | ((uint)f2b(acc[h][1] * inv[h]) << 16);
        o.y = (uint)f2b(acc[h][2] * inv[h]) | ((uint)f2b(acc[h][3] * inv[h]) << 16);
        *(uint2*)(zb + (size_t)n * 256 + h * 64 + sl * 4) = o;
    }
}

// ---------------------------------------------------------------------------
// Final MLP heads. One wave per batch row.
// ---------------------------------------------------------------------------
__global__ __launch_bounds__(256) void final_ui(
    const ushort* __restrict__ s0, const ushort* __restrict__ s1,
    const int* __restrict__ uidx, const int* __restrict__ iidx,
    const float* __restrict__ w1, const float* __restrict__ b1,
    const float* __restrict__ w2, const float* __restrict__ b2, float* __restrict__ out)
{
    __shared__ float xs[4][256];
    int tid = threadIdx.x, wid = tid >> 6, lane = tid & 63;
    int r = (blockIdx.x << 2) + wid;
    int u = uidx[r], it = iidx[r];
    xs[wid][lane]       = b2f(s0[(size_t)u * 64 + lane]);
    xs[wid][64 + lane]  = b2f(s1[(size_t)u * 64 + lane]);
    xs[wid][128 + lane] = b2f(s0[(size_t)it * 64 + lane]);
    xs[wid][192 + lane] = b2f(s1[(size_t)it * 64 + lane]);
    __syncthreads();
    int c = lane << 1;
    float a0 = b1[c], a1 = b1[c + 1];
    for (int k = 0; k < 256; k++) {
        float xv = xs[wid][k];
        float2 wv = *(const float2*)(w1 + (size_t)k * 128 + c);
        a0 = fmaf(xv, wv.x, a0);
        a1 = fmaf(xv, wv.y, a1);
    }
    a0 = fmaxf(a0, 0.f);
    a1 = fmaxf(a1, 0.f);
    float2 w2v = *(const float2*)(w2 + c);
    float p = a0 * w2v.x + a1 * w2v.y;
#pragma unroll
    for (int mm = 1; mm < 64; mm <<= 1) p += __shfl_xor(p, mm);
    if (lane == 0) out[r] = 1.f / (1.f + __expf(-(p + b2[0])));
}

__global__ __launch_bounds__(256) void final_sg(
    const ushort* __restrict__ s0, const ushort* __restrict__ s1,
    const int* __restrict__ gidx,
    const float* __restrict__ w1, const float* __restrict__ b1,
    const float* __restrict__ w2, const float* __restrict__ b2, float* __restrict__ out)
{
    __shared__ float xs[4][128];
    int tid = threadIdx.x, wid = tid >> 6, lane = tid & 63;
    int r = (blockIdx.x << 2) + wid;
    int n = gidx[r];
    xs[wid][lane]      = b2f(s0[(size_t)n * 64 + lane]);
    xs[wid][64 + lane] = b2f(s1[(size_t)n * 64 + lane]);
    __syncthreads();
    int c = lane << 1;
    float a0 = b1[c], a1 = b1[c + 1];
    for (int k = 0; k < 128; k++) {
        float xv = xs[wid][k];
        float2 wv = *(const float2*)(w1 + (size_t)k * 128 + c);
        a0 = fmaf(xv, wv.x, a0);
        a1 = fmaf(xv, wv.y, a1);
    }
    a0 = fmaxf(a0, 0.f);
    a1 = fmaxf(a1, 0.f);
    float2 w2v = *(const float2*)(w2 + c);
    float p = a0 * w2v.x + a1 * w2v.y;
#pragma unroll
    for (int mm = 1; mm < 64; mm <<= 1) p += __shfl_xor(p, mm);
    if (lane == 0) out[r] = 1.f / (1.f + __expf(-(p + b2[0])));
}

// ---------------------------------------------------------------------------
extern "C" void kernel_launch(void* const* d_in, const int* in_sizes, int n_in,
                              void* d_out, int out_size, void* d_ws, size_t ws_size,
                              hipStream_t stream)
{
    const float* x       = (const float*)d_in[0];
    const float* efeat   = (const float*)d_in[1];
    const float* efeat2  = (const float*)d_in[2];
    const float* mask1   = (const float*)d_in[3];
    const float* mask2   = (const float*)d_in[4];
    const int*   src     = (const int*)d_in[5];
    const int*   dst     = (const int*)d_in[6];
    const int*   uidx    = (const int*)d_in[7];
    const int*   iidx    = (const int*)d_in[8];
    const int*   gidx    = (const int*)d_in[9];
    const float* loc_wni = (const float*)d_in[10];
    const float* loc_wnj = (const float*)d_in[11];
    const float* loc_we  = (const float*)d_in[12];
    const float* loc_attn= (const float*)d_in[13];
    const float* loc_wnode=(const float*)d_in[14];
    const float* agg1_w  = (const float*)d_in[15];
    const float* agg1_b  = (const float*)d_in[16];
    const float* glob_wni= (const float*)d_in[17];
    const float* glob_wnj= (const float*)d_in[18];
    const float* glob_we = (const float*)d_in[19];
    const float* glob_attn=(const float*)d_in[20];
    const float* glob_wnode=(const float*)d_in[21];
    const float* agg2_w  = (const float*)d_in[22];
    const float* agg2_b  = (const float*)d_in[23];
    const float* w1_ui   = (const float*)d_in[24];
    const float* b1_ui   = (const float*)d_in[25];
    const float* w1_sg   = (const float*)d_in[26];
    const float* b1_sg   = (const float*)d_in[27];
    const float* w2_ui   = (const float*)d_in[28];
    const float* b2_ui   = (const float*)d_in[29];
    const float* w2_sg   = (const float*)d_in[30];
    const float* b2_sg   = (const float*)d_in[31];

    // workspace carve (all offsets 256B-aligned)
    char* wsp = (char*)d_ws;
    auto carve = [&](size_t bytes) { char* p = wsp; wsp += (bytes + 255) & ~(size_t)255; return p; };
    ushort* zb    = (ushort*)carve((size_t)NN * 256 * 2);
    ushort* hb[5];
    for (int i = 0; i < 5; i++) hb[i] = (ushort*)carve((size_t)NN * 64 * 2);
    float*  scv   = (float*)carve((size_t)NE * 16);
    float*  m1p   = (float*)carve((size_t)NE * 4);
    float*  m2p   = (float*)carve((size_t)NE * 4);
    int*    srcp  = (int*)carve((size_t)NE * 4);
    int*    dstp  = (int*)carve((size_t)NE * 4);
    int*    eidx  = (int*)carve((size_t)NE * 4);
    ushort* Bsc   = (ushort*)carve(4 * 24576 * 2);
    ushort* Bfold = (ushort*)carve(4 * 16384 * 2);
    int* deg      = (int*)carve(NN * 4);
    int* rowptr   = (int*)carve((NN + 4) * 4);
    int* partials = (int*)carve(256 * 4);

    // ---- weight prep (state-independent) + CSR build + fused scatter ----
    k_prep_score_all<<<384, 256, 0, stream>>>(loc_we, glob_we, loc_wni, glob_wni,
                                              loc_wnj, glob_wnj, Bsc);
    k_fold_all<<<256, 256, 0, stream>>>(loc_wnode, agg1_w, glob_wnode, agg2_w, Bfold);
    hipMemsetAsync(deg, 0, NN * sizeof(int), stream);
    k_count<<<1280, 256, 0, stream>>>(dst, deg, NE);
    scan_local<<<196, 256, 0, stream>>>(deg, rowptr, partials, NN);
    scan_partials<<<1, 256, 0, stream>>>(partials, 196);
    scan_add<<<196, 256, 0, stream>>>(rowptr, partials, NN, NE);
    hipMemsetAsync(deg, 0, NN * sizeof(int), stream);
    k_scatter_perm<<<1280, 256, 0, stream>>>(dst, rowptr, deg, src, mask1, mask2,
                                             srcp, dstp, eidx, m1p, m2p, NE);
    k_cvt<<<3200, 256, 0, stream>>>(x, hb[0], NN * 64);

    auto egat = [&](const ushort* hin, int e, const float* maskp, const float* attn,
                    const float* aggb, int act, ushort* hout) {
        int is_glob = e & 1;
        // scores: one GEMM with A = [ef | h[src] | h[dst]], B = [we; wni; wnj]
        if (is_glob)
            score_gemm<<<5000, 256, 0, stream>>>(efeat2, 64, 64, 64, 192,
                                                 Bsc + e * 24576, hin,
                                                 eidx, srcp, dstp, attn, scv);
        else
            score_gemm<<<5000, 256, 0, stream>>>(efeat, 16, 16, 32, 160,
                                                 Bsc + e * 24576, hin,
                                                 eidx, srcp, dstp, attn, scv);
        node_fused<<<NN / 16, 256, 0, stream>>>(scv, rowptr, srcp, maskp, hin, zb);
        gemm_agg<<<782, 256, 0, stream>>>(zb, NN, Bfold + e * 16384, aggb, act, hout);
    };

    egat(hb[0], 0, m1p, loc_attn,        agg1_b,      0, hb[1]);
    egat(hb[1], 1, m2p, glob_attn,       agg2_b,      1, hb[2]);
    egat(hb[2], 2, m1p, loc_attn + 128,  agg1_b + 64, 0, hb[3]);
    egat(hb[3], 3, m2p, glob_attn + 128, agg2_b + 64, 1, hb[4]);

    float* out = (float*)d_out;
    final_sg<<<BATCH / 4, 256, 0, stream>>>(hb[2], hb[4], gidx, w1_sg, b1_sg, w2_sg, b2_sg, out);
    final_ui<<<BATCH / 4, 256, 0, stream>>>(hb[1], hb[3], uidx, iidx, w1_ui, b1_ui, w2_ui, b2_ui, out + BATCH);
}

// Round 12
// 593.256 us; speedup vs baseline: 1.1068x; 1.0584x over previous
//
#include <hip/hip_runtime.h>
#include <math.h>

// EGAT GNN forward — round 12: R11 (transposed fragment-direct score GEMM,
// 590us) + DETERMINISTIC CSR build. R11 failed only the post-timing re-check:
// atomicAdd scatter gave a different within-node edge order per call ->
// different fp32 sum order -> bf16 z flips -> absmax drifted over threshold.
// Now: atomic scatter fills eidx ranks, per-node insertion sort restores
// original-index order (matches numpy reference's segment-sum order), then a
// coalesced pass emits srcp/dstp/m1p/m2p. Bit-identical output every call.
#define NN 50000      // N_NODES
#define NE 320000     // N_EDGES
#define BATCH 4096

typedef __bf16 bf16x8 __attribute__((ext_vector_type(8)));
typedef float floatx4 __attribute__((ext_vector_type(4)));
typedef unsigned short ushort;
typedef unsigned int uint;

__device__ __forceinline__ float lrelu02(float x) { return x > 0.f ? x : 0.2f * x; }
__device__ __forceinline__ float b2f(ushort h) { return __uint_as_float(((uint)h) << 16); }
__device__ __forceinline__ float b2f_lo(uint u) { return __uint_as_float(u << 16); }
__device__ __forceinline__ float b2f_hi(uint u) { return __uint_as_float(u & 0xffff0000u); }
__device__ __forceinline__ ushort f2b(float x) {
    uint u = __float_as_uint(x);
    return (ushort)((u + 0x7fffu + ((u >> 16) & 1u)) >> 16);  // RNE
}

// ---------------------------------------------------------------------------
// Transposed score kernel. Per wave: 16 edges (CSR positions row0+16w+0..15).
// A operand = weights [we|wni|wnj] (128 f-dims x KTOT), LDS, fragment-ordered.
// B operand = edge data [ef | h[src] | h[dst]], per-lane 16B direct global
// fragments, prefetched before the single barrier.
// acc[c][r] = f[fdim=16c+quad*4+r] of edge l16 (fp32, pre-lrelu).
// ---------------------------------------------------------------------------
template <int GLOB>
__global__ __launch_bounds__(256) void score_frag(
    const float* __restrict__ ef,
    const ushort* __restrict__ Bfrag,   // fragment-ordered weights, 128*KTOT
    const ushort* __restrict__ hb,      // N x 64 bf16 layer input
    const int* __restrict__ eidx, const int* __restrict__ srcv,
    const int* __restrict__ dstv,
    const float* __restrict__ attn, float* __restrict__ scv)
{
    constexpr int KTOT = GLOB ? 192 : 160;
    constexpr int NR = KTOT / 32;        // k-rounds: 6 / 5
    constexpr int EFR = GLOB ? 2 : 1;    // ef rounds
    constexpr int LDA = GLOB ? 64 : 16;
    __shared__ __align__(16) ushort As[128 * KTOT];
    const int tid = threadIdx.x;
    const int w = tid >> 6, lane = tid & 63;
    const int quad = lane >> 4, l16 = lane & 15;
    const int row = (blockIdx.x << 6) + 16 * w + l16;   // this lane's edge

    const int e_o = eidx[row];
    const int s_n = srcv[row];
    const int d_n = dstv[row];

    // edge-data fragments (B operand), all issued before the barrier
    bf16x8 bfr[NR];
#pragma unroll
    for (int rnd = 0; rnd < EFR; rnd++) {
        uint4 av = make_uint4(0u, 0u, 0u, 0u);
        int k0 = rnd * 32 + quad * 8;
        if (GLOB || quad < 2) {          // loc: cols >=16 are zero-pad
            const float* ap = ef + (size_t)e_o * LDA + k0;
            float4 f0 = *(const float4*)ap;
            float4 f1 = *(const float4*)(ap + 4);
            av.x = (uint)f2b(f0.x) | ((uint)f2b(f0.y) << 16);
            av.y = (uint)f2b(f0.z) | ((uint)f2b(f0.w) << 16);
            av.z = (uint)f2b(f1.x) | ((uint)f2b(f1.y) << 16);
            av.w = (uint)f2b(f1.z) | ((uint)f2b(f1.w) << 16);
        }
        *(uint4*)&bfr[rnd] = av;
    }
#pragma unroll
    for (int rr = 0; rr < 2; rr++)
        bfr[EFR + rr] = *(const bf16x8*)(hb + (size_t)s_n * 64 + rr * 32 + quad * 8);
#pragma unroll
    for (int rr = 0; rr < 2; rr++)
        bfr[EFR + 2 + rr] = *(const bf16x8*)(hb + (size_t)d_n * 64 + rr * 32 + quad * 8);

    // stage fragment-ordered weights (straight copy)
    for (int i = tid; i < 128 * KTOT / 8; i += 256)
        *(uint4*)(As + (size_t)i * 8) = *(const uint4*)(Bfrag + (size_t)i * 8);
    __syncthreads();

    floatx4 acc[8];
#pragma unroll
    for (int c = 0; c < 8; c++)
#pragma unroll
        for (int r = 0; r < 4; r++) acc[c][r] = 0.f;

#pragma unroll
    for (int rnd = 0; rnd < NR; rnd++) {
#pragma unroll
        for (int c = 0; c < 8; c++) {
            bf16x8 afr = *(const bf16x8*)(As + ((size_t)(c * NR + rnd) * 64 + lane) * 8);
            acc[c] = __builtin_amdgcn_mfma_f32_16x16x32_bf16(afr, bfr[rnd], acc[c], 0, 0, 0);
        }
    }

    // epilogue: in-lane attn dot (lane owns 32 f-dims of its edge)
    float ph[4] = {0.f, 0.f, 0.f, 0.f};
#pragma unroll
    for (int c = 0; c < 8; c++) {
        int fbase = 16 * c + quad * 4;
        float4 at4 = *(const float4*)(attn + fbase);    // attn flat 128
        float v = lrelu02(acc[c][0]) * at4.x;
        v = fmaf(lrelu02(acc[c][1]), at4.y, v);
        v = fmaf(lrelu02(acc[c][2]), at4.z, v);
        v = fmaf(lrelu02(acc[c][3]), at4.w, v);
        ph[fbase >> 5] += v;
    }
#pragma unroll
    for (int h = 0; h < 4; h++) {
        ph[h] += __shfl_xor(ph[h], 16);
        ph[h] += __shfl_xor(ph[h], 32);
    }
    if (quad == 0)
        *(float4*)(scv + (size_t)row * 4) = make_float4(ph[0], ph[1], ph[2], ph[3]);
}

// ---------------------------------------------------------------------------
// Aggregation GEMM (R8 skeleton): z (M x 256 bf16) @ Bfold^T -> act -> M x 64.
// ---------------------------------------------------------------------------
__global__ __launch_bounds__(256) void gemm_agg(
    const ushort* __restrict__ A, int M,
    const ushort* __restrict__ Bt,    // 64 x 256
    const float* __restrict__ bias, int act,
    ushort* __restrict__ outb)
{
    __shared__ __align__(16) ushort As[64 * 32];
    __shared__ __align__(16) ushort Bs[64 * 32];
    const int tid = threadIdx.x;
    const int row0 = blockIdx.x << 6;
    const int w = tid >> 6, lane = tid & 63;
    const int quad = lane >> 4, l16 = lane & 15;
    const int arow = tid >> 2, c0 = (tid & 3) << 3;
    const int agrow = row0 + arow;

    floatx4 acc[4];
#pragma unroll
    for (int c = 0; c < 4; c++)
#pragma unroll
        for (int r = 0; r < 4; r++) acc[c][r] = 0.f;

    for (int kt = 0; kt < 256; kt += 32) {
        uint4 av = make_uint4(0u, 0u, 0u, 0u);
        if (agrow < M)
            av = *(const uint4*)(A + (size_t)agrow * 256 + kt + c0);
        *(uint4*)(As + arow * 32 + c0) = av;
        {
            int bn = tid >> 2, bk = (tid & 3) << 3;
            *(uint4*)(Bs + bn * 32 + bk) = *(const uint4*)(Bt + (size_t)bn * 256 + kt + bk);
        }
        __syncthreads();
        bf16x8 af = *(const bf16x8*)(As + (16 * w + l16) * 32 + quad * 8);
#pragma unroll
        for (int c = 0; c < 4; c++) {
            bf16x8 bfv = *(const bf16x8*)(Bs + (16 * c + l16) * 32 + quad * 8);
            acc[c] = __builtin_amdgcn_mfma_f32_16x16x32_bf16(af, bfv, acc[c], 0, 0, 0);
        }
        if (kt + 32 < 256) __syncthreads();
    }
#pragma unroll
    for (int r = 0; r < 4; r++) {
        int gr = row0 + 16 * w + quad * 4 + r;
        if (gr < M) {
#pragma unroll
            for (int c = 0; c < 4; c++) {
                int col = 16 * c + l16;
                float v = acc[c][r] + bias[col];
                if (act == 0) v = v > 0.f ? v : (__expf(v) - 1.f);
                else          v = v > 0.f ? v : 0.01f * v;
                outb[(size_t)gr * 64 + col] = f2b(v);
            }
        }
    }
}

// ---------------------------------------------------------------------------
// Deterministic CSR build: histogram -> scan -> atomic rank scatter (eidx only)
// -> per-node insertion sort (original-index order) -> coalesced emit.
// ---------------------------------------------------------------------------
__global__ void k_count(const int* __restrict__ dst, int* __restrict__ deg, int E)
{
    for (int i = blockIdx.x * blockDim.x + threadIdx.x; i < E; i += gridDim.x * blockDim.x)
        atomicAdd(&deg[dst[i]], 1);
}

__global__ __launch_bounds__(256) void scan_local(
    const int* __restrict__ deg, int* __restrict__ rowptr, int* __restrict__ partials, int N)
{
    __shared__ int sd[256];
    int tid = threadIdx.x;
    int i = blockIdx.x * 256 + tid;
    int v = (i < N) ? deg[i] : 0;
    sd[tid] = v; __syncthreads();
#pragma unroll
    for (int off = 1; off < 256; off <<= 1) {
        int t = (tid >= off) ? sd[tid - off] : 0;
        __syncthreads();
        sd[tid] += t;
        __syncthreads();
    }
    if (i < N) rowptr[i] = sd[tid] - v;
    if (tid == 255) partials[blockIdx.x] = sd[255];
}

__global__ __launch_bounds__(256) void scan_partials(int* __restrict__ partials, int nb)
{
    __shared__ int sd[256];
    int tid = threadIdx.x;
    int v = (tid < nb) ? partials[tid] : 0;
    sd[tid] = v; __syncthreads();
#pragma unroll
    for (int off = 1; off < 256; off <<= 1) {
        int t = (tid >= off) ? sd[tid - off] : 0;
        __syncthreads();
        sd[tid] += t;
        __syncthreads();
    }
    if (tid < nb) partials[tid] = sd[tid] - v;
}

__global__ void scan_add(int* __restrict__ rowptr, const int* __restrict__ partials, int N, int E)
{
    int i = blockIdx.x * 256 + threadIdx.x;
    if (i < N) rowptr[i] += partials[i >> 8];
    if (i == 0) rowptr[N] = E;
}

__global__ void k_scatter(const int* __restrict__ dst, const int* __restrict__ rowptr,
                          int* __restrict__ cnt, int* __restrict__ eidx, int E)
{
    for (int i = blockIdx.x * blockDim.x + threadIdx.x; i < E; i += gridDim.x * blockDim.x) {
        int d = dst[i];
        int p = rowptr[d] + atomicAdd(&cnt[d], 1);
        eidx[p] = i;
    }
}

// one thread per node: insertion-sort its bucket ascending (deterministic,
// matches reference's index-order segment sums). Avg degree 6.4.
__global__ void k_sort_buckets(const int* __restrict__ rowptr, int* __restrict__ eidx, int N)
{
    int n = blockIdx.x * blockDim.x + threadIdx.x;
    if (n >= N) return;
    int beg = rowptr[n], end = rowptr[n + 1];
    for (int i = beg + 1; i < end; i++) {
        int v = eidx[i];
        int j = i - 1;
        while (j >= beg && eidx[j] > v) { eidx[j + 1] = eidx[j]; j--; }
        eidx[j + 1] = v;
    }
}

__global__ void k_emit_perm(const int* __restrict__ eidx, const int* __restrict__ src,
                            const int* __restrict__ dst,
                            const float* __restrict__ m1, const float* __restrict__ m2,
                            int* __restrict__ srcp, int* __restrict__ dstp,
                            float* __restrict__ m1p, float* __restrict__ m2p, int E)
{
    int p = blockIdx.x * blockDim.x + threadIdx.x;
    if (p < E) {
        int e = eidx[p];
        srcp[p] = src[e];
        dstp[p] = dst[e];
        m1p[p] = m1[e];
        m2p[p] = m2[e];
    }
}

__global__ void k_cvt(const float* __restrict__ in, ushort* __restrict__ out, int n)
{
    for (int i = blockIdx.x * blockDim.x + threadIdx.x; i < n; i += gridDim.x * blockDim.x)
        out[i] = f2b(in[i]);
}

// ---------------------------------------------------------------------------
// Weight prep. Bsc[e] = fragment-ordered [we|wni|wnj] for the transposed
// score kernel: out index o -> j=o&7, lane=(o>>3)&63, t=o>>9, c=t/NR,
// rnd=t%NR; m=16c+(lane&15), k=32rnd+(lane>>4)*8+j.
// ---------------------------------------------------------------------------
__global__ void k_prep_score_all(const float* __restrict__ loc_we, const float* __restrict__ glob_we,
                                 const float* __restrict__ loc_wni, const float* __restrict__ glob_wni,
                                 const float* __restrict__ loc_wnj, const float* __restrict__ glob_wnj,
                                 ushort* __restrict__ B)   // 4 x 24576 slots
{
    int idx = blockIdx.x * 256 + threadIdx.x;   // 4*24576 = 98304
    if (idx >= 4 * 24576) return;
    int e = idx / 24576, rem = idx % 24576;
    int layer = e >> 1, gl = e & 1;
    int KTOT = gl ? 192 : 160;
    int NR = KTOT / 32;
    int ef_end = gl ? 64 : 32;
    int ef_real = gl ? 64 : 16;
    if (rem >= 128 * KTOT) return;
    int j = rem & 7, lane = (rem >> 3) & 63, t = rem >> 9;
    int c = t / NR, rnd = t % NR;
    int m = 16 * c + (lane & 15);
    int k = 32 * rnd + (lane >> 4) * 8 + j;
    const float* we  = (gl ? glob_we  + layer * 64 * 128 : loc_we  + layer * 16 * 128);
    const float* wni = (gl ? glob_wni : loc_wni) + layer * 64 * 128;
    const float* wnj = (gl ? glob_wnj : loc_wnj) + layer * 64 * 128;
    float v;
    if (k < ef_end)            v = (k < ef_real) ? we[k * 128 + m] : 0.f;
    else if (k < ef_end + 64)  v = wni[(k - ef_end) * 128 + m];
    else                       v = wnj[(k - ef_end - 64) * 128 + m];
    B[e * 24576 + rem] = f2b(v);
}

// W'[h*64+i, j] = sum_k wnode[i, h*64+k] * aggw[h*64+k, j]; stored transposed (64 x 256)
__global__ void k_fold_all(const float* __restrict__ loc_wnode, const float* __restrict__ agg1_w,
                           const float* __restrict__ glob_wnode, const float* __restrict__ agg2_w,
                           ushort* __restrict__ B)  // 4 x (64 x 256)
{
    int e = blockIdx.x >> 6;
    int idx = (blockIdx.x & 63) * 256 + threadIdx.x;  // 16384
    int layer = e >> 1, gl = e & 1;
    const float* wnode = (gl ? glob_wnode : loc_wnode) + layer * 64 * 256;
    const float* aggw  = (gl ? agg2_w : agg1_w) + layer * 256 * 64;
    int j = idx >> 8, col = idx & 255;
    int h = col >> 6, ii = col & 63;
    float s = 0.f;
#pragma unroll 8
    for (int k = 0; k < 64; k++)
        s = fmaf(wnode[ii * 256 + h * 64 + k], aggw[(h * 64 + k) * 64 + j], s);
    B[e * 16384 + j * 256 + col] = f2b(s);
}

// ---------------------------------------------------------------------------
// Node kernel, zero cross-lane ops: one 16-lane group per node (all 4 heads),
// 16 groups per block, grid NN/16.
// ---------------------------------------------------------------------------
__global__ __launch_bounds__(256) void node_fused(
    const float* __restrict__ scv,      // E x 4 fp32 (CSR order)
    const int* __restrict__ rowptr, const int* __restrict__ srcp,
    const float* __restrict__ maskp,
    const ushort* __restrict__ hsrc,    // N x 64 bf16 (layer input)
    ushort* __restrict__ zb)            // N x 256 bf16
{
    int tid = threadIdx.x;
    int n = (blockIdx.x << 4) | (tid >> 4);   // 16 groups/block, one node each
    int sl = tid & 15;
    int beg = rowptr[n], end = rowptr[n + 1];
    float l0 = 0.f, l1 = 0.f, l2 = 0.f, l3 = 0.f;
    float acc[4][4] = {};
#pragma unroll 2
    for (int i = beg; i < end; i++) {
        float4 s4 = *(const float4*)(scv + (size_t)i * 4);   // broadcast in group
        float mk = maskp[i];
        int s = srcp[i];
        uint2 hvv = *(const uint2*)(hsrc + (size_t)s * 64 + sl * 4);  // 128B/group
        float t0 = __expf(s4.x), t1 = __expf(s4.y), t2 = __expf(s4.z), t3 = __expf(s4.w);
        l0 += t0; l1 += t1; l2 += t2; l3 += t3;
        float a0 = t0 * mk, a1 = t1 * mk, a2 = t2 * mk, a3 = t3 * mk;
        float hv[4] = { b2f_lo(hvv.x), b2f_hi(hvv.x), b2f_lo(hvv.y), b2f_hi(hvv.y) };
#pragma unroll
        for (int c = 0; c < 4; c++) {
            acc[0][c] = fmaf(a0, hv[c], acc[0][c]);
            acc[1][c] = fmaf(a1, hv[c], acc[1][c]);
            acc[2][c] = fmaf(a2, hv[c], acc[2][c]);
            acc[3][c] = fmaf(a3, hv[c], acc[3][c]);
        }
    }
    float inv[4] = { 1.f / (l0 + 1e-9f), 1.f / (l1 + 1e-9f),
                     1.f / (l2 + 1e-9f), 1.f / (l3 + 1e-9f) };
#pragma unroll
    for (int h = 0; h < 4; h++) {
        uint2 o;
        o.x = (uint)f2b(acc[h][0] * inv[h]) | ((uint)f2b(acc[h][1] * inv[h]) << 16);
        o.y = (uint)f2b(acc[h][2] * inv[h]) | ((uint)f2b(acc[h][3] * inv[h]) << 16);
        *(uint2*)(zb + (size_t)n * 256 + h * 64 + sl * 4) = o;
    }
}

// ---------------------------------------------------------------------------
// Final MLP heads. One wave per batch row.
// ---------------------------------------------------------------------------
__global__ __launch_bounds__(256) void final_ui(
    const ushort* __restrict__ s0, const ushort* __restrict__ s1,
    const int* __restrict__ uidx, const int* __restrict__ iidx,
    const float* __restrict__ w1, const float* __restrict__ b1,
    const float* __restrict__ w2, const float* __restrict__ b2, float* __restrict__ out)
{
    __shared__ float xs[4][256];
    int tid = threadIdx.x, wid = tid >> 6, lane = tid & 63;
    int r = (blockIdx.x << 2) + wid;
    int u = uidx[r], it = iidx[r];
    xs[wid][lane]       = b2f(s0[(size_t)u * 64 + lane]);
    xs[wid][64 + lane]  = b2f(s1[(size_t)u * 64 + lane]);
    xs[wid][128 + lane] = b2f(s0[(size_t)it * 64 + lane]);
    xs[wid][192 + lane] = b2f(s1[(size_t)it * 64 + lane]);
    __syncthreads();
    int c = lane << 1;
    float a0 = b1[c], a1 = b1[c + 1];
    for (int k = 0; k < 256; k++) {
        float xv = xs[wid][k];
        float2 wv = *(const float2*)(w1 + (size_t)k * 128 + c);
        a0 = fmaf(xv, wv.x, a0);
        a1 = fmaf(xv, wv.y, a1);
    }
    a0 = fmaxf(a0, 0.f);
    a1 = fmaxf(a1, 0.f);
    float2 w2v = *(const float2*)(w2 + c);
    float p = a0 * w2v.x + a1 * w2v.y;
#pragma unroll
    for (int mm = 1; mm < 64; mm <<= 1) p += __shfl_xor(p, mm);
    if (lane == 0) out[r] = 1.f / (1.f + __expf(-(p + b2[0])));
}

__global__ __launch_bounds__(256) void final_sg(
    const ushort* __restrict__ s0, const ushort* __restrict__ s1,
    const int* __restrict__ gidx,
    const float* __restrict__ w1, const float* __restrict__ b1,
    const float* __restrict__ w2, const float* __restrict__ b2, float* __restrict__ out)
{
    __shared__ float xs[4][128];
    int tid = threadIdx.x, wid = tid >> 6, lane = tid & 63;
    int r = (blockIdx.x << 2) + wid;
    int n = gidx[r];
    xs[wid][lane]      = b2f(s0[(size_t)n * 64 + lane]);
    xs[wid][64 + lane] = b2f(s1[(size_t)n * 64 + lane]);
    __syncthreads();
    int c = lane << 1;
    float a0 = b1[c], a1 = b1[c + 1];
    for (int k = 0; k < 128; k++) {
        float xv = xs[wid][k];
        float2 wv = *(const float2*)(w1 + (size_t)k * 128 + c);
        a0 = fmaf(xv, wv.x, a0);
        a1 = fmaf(xv, wv.y, a1);
    }
    a0 = fmaxf(a0, 0.f);
    a1 = fmaxf(a1, 0.f);
    float2 w2v = *(const float2*)(w2 + c);
    float p = a0 * w2v.x + a1 * w2v.y;
#pragma unroll
    for (int mm = 1; mm < 64; mm <<= 1) p += __shfl_xor(p, mm);
    if (lane == 0) out[r] = 1.f / (1.f + __expf(-(p + b2[0])));
}

// ---------------------------------------------------------------------------
extern "C" void kernel_launch(void* const* d_in, const int* in_sizes, int n_in,
                              void* d_out, int out_size, void* d_ws, size_t ws_size,
                              hipStream_t stream)
{
    const float* x       = (const float*)d_in[0];
    const float* efeat   = (const float*)d_in[1];
    const float* efeat2  = (const float*)d_in[2];
    const float* mask1   = (const float*)d_in[3];
    const float* mask2   = (const float*)d_in[4];
    const int*   src     = (const int*)d_in[5];
    const int*   dst     = (const int*)d_in[6];
    const int*   uidx    = (const int*)d_in[7];
    const int*   iidx    = (const int*)d_in[8];
    const int*   gidx    = (const int*)d_in[9];
    const float* loc_wni = (const float*)d_in[10];
    const float* loc_wnj = (const float*)d_in[11];
    const float* loc_we  = (const float*)d_in[12];
    const float* loc_attn= (const float*)d_in[13];
    const float* loc_wnode=(const float*)d_in[14];
    const float* agg1_w  = (const float*)d_in[15];
    const float* agg1_b  = (const float*)d_in[16];
    const float* glob_wni= (const float*)d_in[17];
    const float* glob_wnj= (const float*)d_in[18];
    const float* glob_we = (const float*)d_in[19];
    const float* glob_attn=(const float*)d_in[20];
    const float* glob_wnode=(const float*)d_in[21];
    const float* agg2_w  = (const float*)d_in[22];
    const float* agg2_b  = (const float*)d_in[23];
    const float* w1_ui   = (const float*)d_in[24];
    const float* b1_ui   = (const float*)d_in[25];
    const float* w1_sg   = (const float*)d_in[26];
    const float* b1_sg   = (const float*)d_in[27];
    const float* w2_ui   = (const float*)d_in[28];
    const float* b2_ui   = (const float*)d_in[29];
    const float* w2_sg   = (const float*)d_in[30];
    const float* b2_sg   = (const float*)d_in[31];

    // workspace carve (all offsets 256B-aligned)
    char* wsp = (char*)d_ws;
    auto carve = [&](size_t bytes) { char* p = wsp; wsp += (bytes + 255) & ~(size_t)255; return p; };
    ushort* zb    = (ushort*)carve((size_t)NN * 256 * 2);
    ushort* hb[5];
    for (int i = 0; i < 5; i++) hb[i] = (ushort*)carve((size_t)NN * 64 * 2);
    float*  scv   = (float*)carve((size_t)NE * 16);
    float*  m1p   = (float*)carve((size_t)NE * 4);
    float*  m2p   = (float*)carve((size_t)NE * 4);
    int*    srcp  = (int*)carve((size_t)NE * 4);
    int*    dstp  = (int*)carve((size_t)NE * 4);
    int*    eidx  = (int*)carve((size_t)NE * 4);
    ushort* Bsc   = (ushort*)carve(4 * 24576 * 2);
    ushort* Bfold = (ushort*)carve(4 * 16384 * 2);
    int* deg      = (int*)carve(NN * 4);
    int* rowptr   = (int*)carve((NN + 4) * 4);
    int* partials = (int*)carve(256 * 4);

    // ---- weight prep (state-independent) + deterministic CSR build ----
    k_prep_score_all<<<384, 256, 0, stream>>>(loc_we, glob_we, loc_wni, glob_wni,
                                              loc_wnj, glob_wnj, Bsc);
    k_fold_all<<<256, 256, 0, stream>>>(loc_wnode, agg1_w, glob_wnode, agg2_w, Bfold);
    hipMemsetAsync(deg, 0, NN * sizeof(int), stream);
    k_count<<<1280, 256, 0, stream>>>(dst, deg, NE);
    scan_local<<<196, 256, 0, stream>>>(deg, rowptr, partials, NN);
    scan_partials<<<1, 256, 0, stream>>>(partials, 196);
    scan_add<<<196, 256, 0, stream>>>(rowptr, partials, NN, NE);
    hipMemsetAsync(deg, 0, NN * sizeof(int), stream);
    k_scatter<<<1280, 256, 0, stream>>>(dst, rowptr, deg, eidx, NE);
    k_sort_buckets<<<196, 256, 0, stream>>>(rowptr, eidx, NN);
    k_emit_perm<<<1250, 256, 0, stream>>>(eidx, src, dst, mask1, mask2,
                                          srcp, dstp, m1p, m2p, NE);
    k_cvt<<<3200, 256, 0, stream>>>(x, hb[0], NN * 64);

    auto egat = [&](const ushort* hin, int e, const float* maskp, const float* attn,
                    const float* aggb, int act, ushort* hout) {
        int is_glob = e & 1;
        if (is_glob)
            score_frag<1><<<5000, 256, 0, stream>>>(efeat2, Bsc + e * 24576, hin,
                                                    eidx, srcp, dstp, attn, scv);
        else
            score_frag<0><<<5000, 256, 0, stream>>>(efeat, Bsc + e * 24576, hin,
                                                    eidx, srcp, dstp, attn, scv);
        node_fused<<<NN / 16, 256, 0, stream>>>(scv, rowptr, srcp, maskp, hin, zb);
        gemm_agg<<<782, 256, 0, stream>>>(zb, NN, Bfold + e * 16384, aggb, act, hout);
    };

    egat(hb[0], 0, m1p, loc_attn,        agg1_b,      0, hb[1]);
    egat(hb[1], 1, m2p, glob_attn,       agg2_b,      1, hb[2]);
    egat(hb[2], 2, m1p, loc_attn + 128,  agg1_b + 64, 0, hb[3]);
    egat(hb[3], 3, m2p, glob_attn + 128, agg2_b + 64, 1, hb[4]);

    float* out = (float*)d_out;
    final_sg<<<BATCH / 4, 256, 0, stream>>>(hb[2], hb[4], gidx, w1_sg, b1_sg, w2_sg, b2_sg, out);
    final_ui<<<BATCH / 4, 256, 0, stream>>>(hb[1], hb[3], uidx, iidx, w1_ui, b1_ui, w2_ui, b2_ui, out + BATCH);
}